// Round 1
// baseline (5367.904 us; speedup 1.0000x reference)
//
#include <hip/hip_runtime.h>

// VectorQuantize on MI355X (gfx950), fp32 baseline.
// Outputs (concatenated float32 in d_out):
//   [0 .. N*DIM)            quantized_st = embeddings[ind]   (numerically)
//   [N*DIM .. N*DIM+N)      ind (as float)
//   [N*DIM+N]               commit_loss
//   [N*DIM+N+1]             perplexity

#define N_VEC 16384
#define M_CODES 8192
#define DIM 256
#define BETA 0.25f

#define TM 64       // rows per workgroup (resident in LDS)
#define TN 64       // codes per tile
#define KB 32       // k-chunk per stage
#define XSTRIDE 257 // LDS row stride for X (bank-conflict-free b128 broadcast)
#define ESTRIDE 33  // LDS row stride for E chunk (2-way = free)

#define SMEM_FLOATS (TM * XSTRIDE + TN * ESTRIDE)
#define SMEM_BYTES (SMEM_FLOATS * 4)

// ---------------------------------------------------------------- e2 = ||e||^2
__global__ __launch_bounds__(256) void e2_kernel(const float* __restrict__ emb,
                                                 float* __restrict__ e2) {
    int wave = threadIdx.x >> 6;
    int lane = threadIdx.x & 63;
    int code = blockIdx.x * 4 + wave;
    float4 v = *(const float4*)(emb + code * DIM + lane * 4);
    float s = v.x * v.x + v.y * v.y + v.z * v.z + v.w * v.w;
    #pragma unroll
    for (int off = 32; off; off >>= 1) s += __shfl_xor(s, off);
    if (lane == 0) e2[code] = s;
}

// ------------------------------------------- fused distance-GEMM + row argmin
__global__ __launch_bounds__(256, 2) void argmin_kernel(
    const float* __restrict__ x, const float* __restrict__ emb,
    const float* __restrict__ e2, float* __restrict__ out_ind_f,
    int* __restrict__ ws_ind, unsigned* __restrict__ counts) {
    extern __shared__ float smem[];
    float* Xs = smem;                 // [TM][XSTRIDE]
    float* Es = smem + TM * XSTRIDE;  // [TN][ESTRIDE]

    const int t = threadIdx.x;
    const int row0 = blockIdx.x * TM;

    // Load X tile (64 rows x 256) once. 4096 float4s / 256 threads = 16 each.
    #pragma unroll
    for (int it = 0; it < 16; ++it) {
        int f4 = it * 256 + t;   // 0..4095
        int r = f4 >> 6;         // 0..63
        int kq = f4 & 63;        // float4 index within row
        float4 v = *(const float4*)(x + (row0 + r) * DIM + kq * 4);
        *(float4*)(&Xs[r * XSTRIDE + kq * 4]) = v;
    }

    const int i = t >> 4;   // row group 0..15  -> rows 4i..4i+3
    const int j = t & 15;   // col group 0..15  -> cols 4j..4j+3

    float best[4];
    int bidx[4];
    #pragma unroll
    for (int m = 0; m < 4; ++m) { best[m] = 3.4e38f; bidx[m] = 0; }

    for (int c0 = 0; c0 < M_CODES; c0 += TN) {
        float acc[4][4];
        #pragma unroll
        for (int m = 0; m < 4; ++m)
            #pragma unroll
            for (int n = 0; n < 4; ++n) acc[m][n] = 0.0f;

        for (int kc = 0; kc < DIM / KB; ++kc) {
            __syncthreads();  // protect Es from previous readers (also covers Xs init)
            {
                // stage E chunk: 64 codes x 32 floats = 512 float4, 2 per thread
                int c = t >> 2;            // 0..63
                int kq = (t & 3) * 8;      // 0,8,16,24
                const float* src = emb + (c0 + c) * DIM + kc * KB + kq;
                float4 a = *(const float4*)(src);
                float4 b = *(const float4*)(src + 4);
                float* dst = &Es[c * ESTRIDE + kq];
                *(float4*)(dst) = a;
                *(float4*)(dst + 4) = b;
            }
            __syncthreads();

            #pragma unroll
            for (int k4 = 0; k4 < KB / 4; ++k4) {
                float4 xv[4], ev[4];
                #pragma unroll
                for (int m = 0; m < 4; ++m)
                    xv[m] = *(const float4*)(&Xs[(4 * i + m) * XSTRIDE + kc * KB + k4 * 4]);
                #pragma unroll
                for (int n = 0; n < 4; ++n)
                    ev[n] = *(const float4*)(&Es[(4 * j + n) * ESTRIDE + k4 * 4]);
                #pragma unroll
                for (int m = 0; m < 4; ++m)
                    #pragma unroll
                    for (int n = 0; n < 4; ++n) {
                        acc[m][n] += xv[m].x * ev[n].x;
                        acc[m][n] += xv[m].y * ev[n].y;
                        acc[m][n] += xv[m].z * ev[n].z;
                        acc[m][n] += xv[m].w * ev[n].w;
                    }
            }
        }

        // score = e2[c] - 2*dot  (x2 and sqrt are argmin-invariant)
        float4 e2v = *(const float4*)(e2 + c0 + 4 * j);
        float e2a[4] = {e2v.x, e2v.y, e2v.z, e2v.w};
        #pragma unroll
        for (int n = 0; n < 4; ++n) {
            int c = c0 + 4 * j + n;
            #pragma unroll
            for (int m = 0; m < 4; ++m) {
                float s = e2a[n] - 2.0f * acc[m][n];
                if (s < best[m]) { best[m] = s; bidx[m] = c; }
            }
        }
    }

    // reduce across the 16 threads (j) sharing each row; ties -> lowest index
    #pragma unroll
    for (int m = 0; m < 4; ++m) {
        float v = best[m];
        int ix = bidx[m];
        #pragma unroll
        for (int off = 1; off < 16; off <<= 1) {
            float v2 = __shfl_xor(v, off);
            int ix2 = __shfl_xor(ix, off);
            if (v2 < v || (v2 == v && ix2 < ix)) { v = v2; ix = ix2; }
        }
        if (j == 0) {
            int r = row0 + 4 * i + m;
            out_ind_f[r] = (float)ix;
            ws_ind[r] = ix;
            atomicAdd(&counts[ix], 1u);
        }
    }
}

// ------------------------------- gather quantized rows + commit-loss partial
__global__ __launch_bounds__(256) void gather_kernel(
    const float* __restrict__ x, const float* __restrict__ emb,
    const int* __restrict__ ws_ind, float* __restrict__ out_q,
    float* __restrict__ loss_acc) {
    __shared__ float partial[4];
    int wave = threadIdx.x >> 6;
    int lane = threadIdx.x & 63;
    int row = blockIdx.x * 4 + wave;
    int idx = ws_ind[row];
    float4 q = *(const float4*)(emb + idx * DIM + lane * 4);
    float4 xv = *(const float4*)(x + row * DIM + lane * 4);
    *(float4*)(out_q + row * DIM + lane * 4) = q;
    float dx = q.x - xv.x, dy = q.y - xv.y, dz = q.z - xv.z, dw = q.w - xv.w;
    float s = dx * dx + dy * dy + dz * dz + dw * dw;
    #pragma unroll
    for (int off = 32; off; off >>= 1) s += __shfl_xor(s, off);
    if (lane == 0) partial[wave] = s;
    __syncthreads();
    if (threadIdx.x == 0)
        atomicAdd(loss_acc, partial[0] + partial[1] + partial[2] + partial[3]);
}

// -------------------------------------------------- entropy / loss finalize
__global__ __launch_bounds__(256) void finalize_kernel(
    const unsigned* __restrict__ counts, const float* __restrict__ loss_acc,
    float* __restrict__ out_scalars) {
    __shared__ float red[256];
    float h = 0.0f;
    for (int c = threadIdx.x; c < M_CODES; c += 256) {
        float p = (float)counts[c] * (1.0f / (float)N_VEC);
        h += p * logf(p + 1e-10f);
    }
    red[threadIdx.x] = h;
    __syncthreads();
    for (int s = 128; s; s >>= 1) {
        if (threadIdx.x < s) red[threadIdx.x] += red[threadIdx.x + s];
        __syncthreads();
    }
    if (threadIdx.x == 0) {
        out_scalars[0] = BETA * loss_acc[0] / (float)(N_VEC * DIM);
        out_scalars[1] = expf(-red[0]);
    }
}

extern "C" void kernel_launch(void* const* d_in, const int* in_sizes, int n_in,
                              void* d_out, int out_size, void* d_ws, size_t ws_size,
                              hipStream_t stream) {
    const float* x = (const float*)d_in[0];
    const float* emb = (const float*)d_in[1];

    float* out = (float*)d_out;
    float* out_q = out;                              // N*DIM
    float* out_ind = out + N_VEC * DIM;              // N
    float* out_scalars = out + N_VEC * DIM + N_VEC;  // 2

    float* e2 = (float*)d_ws;                        // M floats
    unsigned* counts = (unsigned*)(e2 + M_CODES);    // M uints
    int* ws_ind = (int*)(counts + M_CODES);          // N ints
    float* loss_acc = (float*)(ws_ind + N_VEC);      // 1 float

    hipMemsetAsync(counts, 0, M_CODES * sizeof(unsigned), stream);
    hipMemsetAsync(loss_acc, 0, sizeof(float), stream);

    e2_kernel<<<M_CODES / 4, 256, 0, stream>>>(emb, e2);

    hipFuncSetAttribute((const void*)argmin_kernel,
                        hipFuncAttributeMaxDynamicSharedMemorySize, SMEM_BYTES);
    argmin_kernel<<<N_VEC / TM, 256, SMEM_BYTES, stream>>>(x, emb, e2, out_ind,
                                                           ws_ind, counts);

    gather_kernel<<<N_VEC / 4, 256, 0, stream>>>(x, emb, ws_ind, out_q, loss_acc);
    finalize_kernel<<<1, 256, 0, stream>>>(counts, loss_acc, out_scalars);
}

// Round 2
// 297.913 us; speedup vs baseline: 18.0184x; 18.0184x over previous
//
#include <hip/hip_runtime.h>
#include <stdint.h>

// VectorQuantize on MI355X (gfx950) — bf16x3 MFMA distance-GEMM + argmin.
// d_out: [0..N*DIM) quantized (fp32), [N*DIM..+N) ind (fp32), then loss, perplexity.

#define N_VEC 16384
#define M_CODES 8192
#define DIM 256
#define BETA 0.25f

#define NSLICE 8          // M split across blocks
#define SLICE_CODES 1024
#define BM 128            // rows per block
#define BN 128            // codes per inner tile
#define BK 32             // K chunk (bf16) per stage
#define NPART 16          // NSLICE * 2 column halves

typedef __attribute__((ext_vector_type(4))) float f32x4;
typedef __attribute__((ext_vector_type(8))) __bf16 bf16x8;

__device__ __forceinline__ void gll16(const void* g, const void* lds) {
    __builtin_amdgcn_global_load_lds(
        (const __attribute__((address_space(1))) uint32_t*)(uintptr_t)g,
        (__attribute__((address_space(3))) uint32_t*)(uint32_t)(uintptr_t)lds,
        16, 0, 0);
}

__device__ __forceinline__ ushort f2bf(float f) {
    uint32_t u = __float_as_uint(f);
    return (ushort)((u + 0x7FFFu + ((u >> 16) & 1u)) >> 16);  // RNE
}
__device__ __forceinline__ float bf2f(ushort h) {
    return __uint_as_float(((uint32_t)h) << 16);
}

// ------------------------------------------------ split fp32 -> bf16 hi + lo
__global__ __launch_bounds__(256) void split_kernel(const float* __restrict__ in,
                                                    ushort* __restrict__ hi,
                                                    ushort* __restrict__ lo) {
    int i = (blockIdx.x * 256 + threadIdx.x) * 4;
    float4 v = *(const float4*)(in + i);
    ushort h0 = f2bf(v.x), h1 = f2bf(v.y), h2 = f2bf(v.z), h3 = f2bf(v.w);
    ushort l0 = f2bf(v.x - bf2f(h0)), l1 = f2bf(v.y - bf2f(h1));
    ushort l2 = f2bf(v.z - bf2f(h2)), l3 = f2bf(v.w - bf2f(h3));
    *(ushort4*)(hi + i) = make_ushort4(h0, h1, h2, h3);
    *(ushort4*)(lo + i) = make_ushort4(l0, l1, l2, l3);
}

// ---------------------------------------------------------------- e2 = ||e||^2
__global__ __launch_bounds__(256) void e2_kernel(const float* __restrict__ emb,
                                                 float* __restrict__ e2) {
    int wave = threadIdx.x >> 6;
    int lane = threadIdx.x & 63;
    int code = blockIdx.x * 4 + wave;
    float4 v = *(const float4*)(emb + code * DIM + lane * 4);
    float s = v.x * v.x + v.y * v.y + v.z * v.z + v.w * v.w;
    #pragma unroll
    for (int off = 32; off; off >>= 1) s += __shfl_xor(s, off);
    if (lane == 0) e2[code] = s;
}

// ------------------------------- main: bf16x3 MFMA distance GEMM with argmin
__global__ __launch_bounds__(256) void vq_mfma_kernel(
    const ushort* __restrict__ xh, const ushort* __restrict__ xl,
    const ushort* __restrict__ eh, const ushort* __restrict__ el,
    const float* __restrict__ e2g, unsigned long long* __restrict__ partials) {
    // LDS: XH [0,8K) XL [8K,16K) EH [16K,24K) EL [24K,32K); each 128 rows x 64B
    __shared__ char lds[4 * BM * BK * 2];

    const int t = threadIdx.x;
    const int lane = t & 63;
    const int wv = t >> 6;        // wave 0..3
    const int lane15 = lane & 15;
    const int l16 = lane >> 4;    // 0..3

    const int bid = blockIdx.x;
    const int rt = bid & 127;     // row tile
    const int slice = bid >> 7;   // 0..7
    const int row0 = rt * BM;
    const int cslice0 = slice * SLICE_CODES;

    const int wr0 = (wv & 1) * 64;  // wave's row quadrant
    const int wc0 = (wv >> 1) * 64; // wave's col quadrant

    // ---- fragment LDS read addresses (constant; swizzled slot = c16 ^ ((row>>1)&3))
    int byteA[4], byteB[4];
    #pragma unroll
    for (int f = 0; f < 4; ++f) {
        int ra = wr0 + f * 16 + lane15;
        byteA[f] = ra * 64 + (((l16 ^ (ra >> 1)) & 3) << 4);
        int rb = wc0 + f * 16 + lane15;
        byteB[f] = rb * 64 + (((l16 ^ (rb >> 1)) & 3) << 4);
    }

    // ---- staging: wave wv covers LDS 16B-slots [wv*128, wv*128+128) per tile
    // slot s holds global (row = s>>2, c16 = (s&3) ^ ((s>>3)&3))  [inverse swizzle]
    const int s0 = wv * 128 + lane;
    const int s1 = s0 + 64;
    const int r0s = s0 >> 2, r1s = s1 >> 2;
    const int c0s = ((s0 & 3) ^ ((s0 >> 3) & 3)) << 3;  // bf16 elems
    const int c1s = ((s1 & 3) ^ ((s1 >> 3) & 3)) << 3;
    const size_t xoff0 = (size_t)(row0 + r0s) * DIM + c0s;
    const size_t xoff1 = (size_t)(row0 + r1s) * DIM + c1s;
    const size_t eoff0 = (size_t)(cslice0 + r0s) * DIM + c0s;
    const size_t eoff1 = (size_t)(cslice0 + r1s) * DIM + c1s;
    char* ldq0 = lds + wv * 2048;
    char* ldq1 = lds + wv * 2048 + 1024;

    float best[16];
    int bidx[16];
    #pragma unroll
    for (int s = 0; s < 16; ++s) { best[s] = __uint_as_float(0x7f800000u); bidx[s] = 0; }

    for (int ct = 0; ct < SLICE_CODES / BN; ++ct) {
        f32x4 acc[4][4];
        #pragma unroll
        for (int fi = 0; fi < 4; ++fi)
            #pragma unroll
            for (int fj = 0; fj < 4; ++fj) acc[fi][fj] = (f32x4){0.f, 0.f, 0.f, 0.f};

        const ushort* ehp0 = eh + eoff0 + (size_t)ct * BN * DIM;
        const ushort* ehp1 = eh + eoff1 + (size_t)ct * BN * DIM;
        const ushort* elp0 = el + eoff0 + (size_t)ct * BN * DIM;
        const ushort* elp1 = el + eoff1 + (size_t)ct * BN * DIM;

        for (int kc = 0; kc < DIM / BK; ++kc) {
            const int ko = kc * BK;
            gll16(xh + xoff0 + ko, ldq0);
            gll16(xh + xoff1 + ko, ldq1);
            gll16(xl + xoff0 + ko, ldq0 + 8192);
            gll16(xl + xoff1 + ko, ldq1 + 8192);
            gll16(ehp0 + ko, ldq0 + 16384);
            gll16(ehp1 + ko, ldq1 + 16384);
            gll16(elp0 + ko, ldq0 + 24576);
            gll16(elp1 + ko, ldq1 + 24576);
            __syncthreads();  // drains vmcnt -> staged data visible

            bf16x8 ah[4], alo[4], bh[4], blo[4];
            #pragma unroll
            for (int f = 0; f < 4; ++f) {
                ah[f]  = *(const bf16x8*)(lds + byteA[f]);
                alo[f] = *(const bf16x8*)(lds + 8192 + byteA[f]);
                bh[f]  = *(const bf16x8*)(lds + 16384 + byteB[f]);
                blo[f] = *(const bf16x8*)(lds + 24576 + byteB[f]);
            }
            #pragma unroll
            for (int fi = 0; fi < 4; ++fi)
                #pragma unroll
                for (int fj = 0; fj < 4; ++fj) {
                    acc[fi][fj] = __builtin_amdgcn_mfma_f32_16x16x32_bf16(
                        ah[fi], bh[fj], acc[fi][fj], 0, 0, 0);
                    acc[fi][fj] = __builtin_amdgcn_mfma_f32_16x16x32_bf16(
                        ah[fi], blo[fj], acc[fi][fj], 0, 0, 0);
                    acc[fi][fj] = __builtin_amdgcn_mfma_f32_16x16x32_bf16(
                        alo[fi], bh[fj], acc[fi][fj], 0, 0, 0);
                }
            __syncthreads();  // readers done before next stage overwrites
        }

        // epilogue: score = e2[c] - 2*dot; C/D layout col=lane&15, row=(lane>>4)*4+reg
        const int cb = cslice0 + ct * BN + wc0;
        #pragma unroll
        for (int fj = 0; fj < 4; ++fj) {
            const int c = cb + fj * 16 + lane15;
            const float e2v = e2g[c];
            #pragma unroll
            for (int fi = 0; fi < 4; ++fi)
                #pragma unroll
                for (int r = 0; r < 4; ++r) {
                    float sc = e2v - 2.0f * acc[fi][fj][r];
                    const int slot = fi * 4 + r;
                    if (sc < best[slot]) { best[slot] = sc; bidx[slot] = c; }
                }
        }
    }

    // reduce across the 16 lanes sharing each row; ties -> lowest index
    #pragma unroll
    for (int slot = 0; slot < 16; ++slot) {
        float v = best[slot];
        int ix = bidx[slot];
        #pragma unroll
        for (int off = 1; off < 16; off <<= 1) {
            float v2 = __shfl_xor(v, off);
            int ix2 = __shfl_xor(ix, off);
            if (v2 < v || (v2 == v && ix2 < ix)) { v = v2; ix = ix2; }
        }
        if (lane15 == 0) {
            int fi = slot >> 2, r = slot & 3;
            int row = row0 + wr0 + fi * 16 + l16 * 4 + r;
            uint32_t u = __float_as_uint(v);
            uint32_t ord = (u & 0x80000000u) ? ~u : (u | 0x80000000u);
            partials[(size_t)(slice * 2 + (wv >> 1)) * N_VEC + row] =
                ((unsigned long long)ord << 32) | (unsigned)ix;
        }
    }
}

// ------------------------------------------- min over partial slices per row
__global__ __launch_bounds__(256) void reduce_kernel(
    const unsigned long long* __restrict__ partials, float* __restrict__ out_ind,
    int* __restrict__ ws_ind, unsigned* __restrict__ counts) {
    int row = blockIdx.x * 256 + threadIdx.x;
    unsigned long long m = partials[row];
    #pragma unroll
    for (int s = 1; s < NPART; ++s) {
        unsigned long long v = partials[(size_t)s * N_VEC + row];
        if (v < m) m = v;
    }
    int ix = (int)(unsigned)(m & 0xFFFFFFFFull);
    out_ind[row] = (float)ix;
    ws_ind[row] = ix;
    atomicAdd(&counts[ix], 1u);
}

// ------------------------------- gather quantized rows + commit-loss partial
__global__ __launch_bounds__(256) void gather_kernel(
    const float* __restrict__ x, const float* __restrict__ emb,
    const int* __restrict__ ws_ind, float* __restrict__ out_q,
    float* __restrict__ loss_acc) {
    __shared__ float partial[4];
    int wave = threadIdx.x >> 6;
    int lane = threadIdx.x & 63;
    int row = blockIdx.x * 4 + wave;
    int idx = ws_ind[row];
    float4 q = *(const float4*)(emb + idx * DIM + lane * 4);
    float4 xv = *(const float4*)(x + row * DIM + lane * 4);
    *(float4*)(out_q + row * DIM + lane * 4) = q;
    float dx = q.x - xv.x, dy = q.y - xv.y, dz = q.z - xv.z, dw = q.w - xv.w;
    float s = dx * dx + dy * dy + dz * dz + dw * dw;
    #pragma unroll
    for (int off = 32; off; off >>= 1) s += __shfl_xor(s, off);
    if (lane == 0) partial[wave] = s;
    __syncthreads();
    if (threadIdx.x == 0)
        atomicAdd(loss_acc, partial[0] + partial[1] + partial[2] + partial[3]);
}

// -------------------------------------------------- entropy / loss finalize
__global__ __launch_bounds__(256) void finalize_kernel(
    const unsigned* __restrict__ counts, const float* __restrict__ loss_acc,
    float* __restrict__ out_scalars) {
    __shared__ float red[256];
    float h = 0.0f;
    for (int c = threadIdx.x; c < M_CODES; c += 256) {
        float p = (float)counts[c] * (1.0f / (float)N_VEC);
        h += p * logf(p + 1e-10f);
    }
    red[threadIdx.x] = h;
    __syncthreads();
    for (int s = 128; s; s >>= 1) {
        if (threadIdx.x < s) red[threadIdx.x] += red[threadIdx.x + s];
        __syncthreads();
    }
    if (threadIdx.x == 0) {
        out_scalars[0] = BETA * loss_acc[0] / (float)(N_VEC * DIM);
        out_scalars[1] = expf(-red[0]);
    }
}

extern "C" void kernel_launch(void* const* d_in, const int* in_sizes, int n_in,
                              void* d_out, int out_size, void* d_ws, size_t ws_size,
                              hipStream_t stream) {
    const float* x = (const float*)d_in[0];
    const float* emb = (const float*)d_in[1];

    float* out = (float*)d_out;
    float* out_q = out;                                   // N*DIM
    float* out_ind = out + (size_t)N_VEC * DIM;           // N
    float* out_scalars = out_ind + N_VEC;                 // 2

    // x hi/lo scratch lives in d_out's quantized region (16 MB, rewritten by gather)
    ushort* xh = (ushort*)out;                            // 8 MB
    ushort* xl = xh + (size_t)N_VEC * DIM;                // 8 MB

    char* wp = (char*)d_ws;
    ushort* eh = (ushort*)wp;  wp += (size_t)M_CODES * DIM * 2;   // 4 MB
    ushort* el = (ushort*)wp;  wp += (size_t)M_CODES * DIM * 2;   // 4 MB
    float* e2 = (float*)wp;    wp += (size_t)M_CODES * 4;         // 32 KB
    unsigned long long* partials = (unsigned long long*)wp;
    wp += (size_t)NPART * N_VEC * 8;                              // 2 MB
    unsigned* counts = (unsigned*)wp; wp += (size_t)M_CODES * 4;  // 32 KB
    int* ws_ind = (int*)wp;    wp += (size_t)N_VEC * 4;           // 64 KB
    float* loss_acc = (float*)wp;                                 // 4 B

    hipMemsetAsync(counts, 0, M_CODES * 4, stream);
    hipMemsetAsync(loss_acc, 0, 4, stream);

    split_kernel<<<N_VEC * DIM / 1024, 256, 0, stream>>>(x, xh, xl);
    split_kernel<<<M_CODES * DIM / 1024, 256, 0, stream>>>(emb, eh, el);
    e2_kernel<<<M_CODES / 4, 256, 0, stream>>>(emb, e2);

    vq_mfma_kernel<<<128 * NSLICE, 256, 0, stream>>>(xh, xl, eh, el, e2, partials);

    reduce_kernel<<<N_VEC / 256, 256, 0, stream>>>(partials, out_ind, ws_ind, counts);
    gather_kernel<<<N_VEC / 4, 256, 0, stream>>>(x, emb, ws_ind, out_q, loss_acc);
    finalize_kernel<<<1, 256, 0, stream>>>(counts, loss_acc, out_scalars);
}

// Round 3
// 277.169 us; speedup vs baseline: 19.3669x; 1.0748x over previous
//
#include <hip/hip_runtime.h>
#include <stdint.h>

// VectorQuantize on MI355X (gfx950) — bf16x3 MFMA distance-GEMM + argmin.
// Round 3: 2-phase double-buffered K-loop (T3), fused prologue/epilogue kernels.
// d_out: [0..N*DIM) quantized (fp32), [N*DIM..+N) ind (fp32), then loss, perplexity.

#define N_VEC 16384
#define M_CODES 8192
#define DIM 256
#define BETA 0.25f

#define NSLICE 8          // M split across blocks
#define SLICE_CODES 1024
#define BM 128            // rows per block
#define BN 128            // codes per inner tile
#define BK 32             // K chunk (bf16) per stage
#define NPART 16          // NSLICE * 2 column halves
#define LDS_HALF 32768    // one pipeline buffer (XH/XL/EH/EL x 8KB)

typedef __attribute__((ext_vector_type(4))) float f32x4;
typedef __attribute__((ext_vector_type(8))) __bf16 bf16x8;

__device__ __forceinline__ void gll16(const void* g, const void* lds) {
    __builtin_amdgcn_global_load_lds(
        (const __attribute__((address_space(1))) uint32_t*)(uintptr_t)g,
        (__attribute__((address_space(3))) uint32_t*)(uint32_t)(uintptr_t)lds,
        16, 0, 0);
}

#define PIPE_SYNC() do { \
    asm volatile("s_waitcnt vmcnt(0)" ::: "memory"); \
    asm volatile("s_barrier" ::: "memory"); \
} while (0)

__device__ __forceinline__ ushort f2bf(float f) {
    uint32_t u = __float_as_uint(f);
    return (ushort)((u + 0x7FFFu + ((u >> 16) & 1u)) >> 16);  // RNE
}
__device__ __forceinline__ float bf2f(ushort h) {
    return __uint_as_float(((uint32_t)h) << 16);
}

// -------------------- fused: split fp32 -> bf16 hi/lo for x and e, plus e2
__global__ __launch_bounds__(256) void prep_kernel(
    const float* __restrict__ x, const float* __restrict__ emb,
    ushort* __restrict__ xh, ushort* __restrict__ xl,
    ushort* __restrict__ eh, ushort* __restrict__ el,
    float* __restrict__ e2) {
    const int wave = threadIdx.x >> 6;
    const int lane = threadIdx.x & 63;
    const int row = blockIdx.x * 4 + wave;  // 0..N_VEC+M_CODES-1

    const float* src;
    ushort* ph;
    ushort* pl;
    bool is_e;
    int er = row - N_VEC;
    if (row < N_VEC) {
        src = x + (size_t)row * DIM;
        ph = xh + (size_t)row * DIM;
        pl = xl + (size_t)row * DIM;
        is_e = false;
    } else {
        src = emb + (size_t)er * DIM;
        ph = eh + (size_t)er * DIM;
        pl = el + (size_t)er * DIM;
        is_e = true;
    }
    float4 v = *(const float4*)(src + lane * 4);
    ushort h0 = f2bf(v.x), h1 = f2bf(v.y), h2 = f2bf(v.z), h3 = f2bf(v.w);
    ushort l0 = f2bf(v.x - bf2f(h0)), l1 = f2bf(v.y - bf2f(h1));
    ushort l2 = f2bf(v.z - bf2f(h2)), l3 = f2bf(v.w - bf2f(h3));
    *(ushort4*)(ph + lane * 4) = make_ushort4(h0, h1, h2, h3);
    *(ushort4*)(pl + lane * 4) = make_ushort4(l0, l1, l2, l3);
    if (is_e) {
        float s = v.x * v.x + v.y * v.y + v.z * v.z + v.w * v.w;
        #pragma unroll
        for (int off = 32; off; off >>= 1) s += __shfl_xor(s, off);
        if (lane == 0) e2[er] = s;
    }
}

// ------------------------------- main: bf16x3 MFMA distance GEMM with argmin
__global__ __launch_bounds__(256, 2) void vq_mfma_kernel(
    const ushort* __restrict__ xh, const ushort* __restrict__ xl,
    const ushort* __restrict__ eh, const ushort* __restrict__ el,
    const float* __restrict__ e2g, unsigned long long* __restrict__ partials) {
    // LDS per buffer: XH [0,8K) XL [8K,16K) EH [16K,24K) EL [24K,32K); x2 buffers
    extern __shared__ char lds[];

    const int t = threadIdx.x;
    const int lane = t & 63;
    const int wv = t >> 6;        // wave 0..3
    const int lane15 = lane & 15;
    const int l16 = lane >> 4;    // 0..3

    const int bid = blockIdx.x;
    const int rt = bid & 127;     // row tile
    const int slice = bid >> 7;   // 0..7
    const int row0 = rt * BM;
    const int cslice0 = slice * SLICE_CODES;

    const int wr0 = (wv & 1) * 64;  // wave's row quadrant
    const int wc0 = (wv >> 1) * 64; // wave's col quadrant

    // ---- fragment LDS read addresses (swizzled slot = c16 ^ ((row>>1)&3))
    int byteA[4], byteB[4];
    #pragma unroll
    for (int f = 0; f < 4; ++f) {
        int ra = wr0 + f * 16 + lane15;
        byteA[f] = ra * 64 + (((l16 ^ (ra >> 1)) & 3) << 4);
        int rb = wc0 + f * 16 + lane15;
        byteB[f] = rb * 64 + (((l16 ^ (rb >> 1)) & 3) << 4);
    }

    // ---- staging: wave wv covers LDS 16B-slots [wv*128, wv*128+128) per tile
    // slot s holds global (row = s>>2, c16 = (s&3) ^ ((s>>3)&3))  [inverse swizzle]
    const int s0 = wv * 128 + lane;
    const int s1 = s0 + 64;
    const int r0s = s0 >> 2, r1s = s1 >> 2;
    const int c0s = ((s0 & 3) ^ ((s0 >> 3) & 3)) << 3;  // bf16 elems
    const int c1s = ((s1 & 3) ^ ((s1 >> 3) & 3)) << 3;
    const ushort* pxh0 = xh + (size_t)(row0 + r0s) * DIM + c0s;
    const ushort* pxh1 = xh + (size_t)(row0 + r1s) * DIM + c1s;
    const ushort* pxl0 = xl + (size_t)(row0 + r0s) * DIM + c0s;
    const ushort* pxl1 = xl + (size_t)(row0 + r1s) * DIM + c1s;
    const ushort* peh0 = eh + (size_t)(cslice0 + r0s) * DIM + c0s;
    const ushort* peh1 = eh + (size_t)(cslice0 + r1s) * DIM + c1s;
    const ushort* pel0 = el + (size_t)(cslice0 + r0s) * DIM + c0s;
    const ushort* pel1 = el + (size_t)(cslice0 + r1s) * DIM + c1s;

    float best[16];
    int bidx[16];
    #pragma unroll
    for (int s = 0; s < 16; ++s) { best[s] = __uint_as_float(0x7f800000u); bidx[s] = 0; }

    f32x4 acc[4][4];
    #pragma unroll
    for (int fi = 0; fi < 4; ++fi)
        #pragma unroll
        for (int fj = 0; fj < 4; ++fj) acc[fi][fj] = (f32x4){0.f, 0.f, 0.f, 0.f};

    // stage one K-step (BK=32 of all four operand tiles) into buffer `buf`
    auto stage = [&](int buf, int ks) {
        const int ct = ks >> 3;
        const int kc = ks & 7;
        const size_t xo = (size_t)(kc << 5);
        const size_t eo = (size_t)ct * ((size_t)BN * DIM) + (kc << 5);
        char* l0 = lds + buf * LDS_HALF + wv * 2048;
        char* l1 = l0 + 1024;
        gll16(pxh0 + xo, l0);
        gll16(pxh1 + xo, l1);
        gll16(pxl0 + xo, l0 + 8192);
        gll16(pxl1 + xo, l1 + 8192);
        gll16(peh0 + eo, l0 + 16384);
        gll16(peh1 + eo, l1 + 16384);
        gll16(pel0 + eo, l0 + 24576);
        gll16(pel1 + eo, l1 + 24576);
    };

    stage(0, 0);
    PIPE_SYNC();

    int cur = 0;
    for (int ks = 0; ks < 64; ++ks) {
        if (ks < 63) stage(cur ^ 1, ks + 1);  // prefetch next step (in flight over MFMA)

        const char* lb = lds + cur * LDS_HALF;
        bf16x8 ah[4], bh[4];
        #pragma unroll
        for (int f = 0; f < 4; ++f) {
            ah[f] = *(const bf16x8*)(lb + byteA[f]);
            bh[f] = *(const bf16x8*)(lb + 16384 + byteB[f]);
        }
        #pragma unroll
        for (int fi = 0; fi < 4; ++fi)
            #pragma unroll
            for (int fj = 0; fj < 4; ++fj)
                acc[fi][fj] = __builtin_amdgcn_mfma_f32_16x16x32_bf16(
                    ah[fi], bh[fj], acc[fi][fj], 0, 0, 0);
        bf16x8 blo[4];
        #pragma unroll
        for (int f = 0; f < 4; ++f) blo[f] = *(const bf16x8*)(lb + 24576 + byteB[f]);
        #pragma unroll
        for (int fi = 0; fi < 4; ++fi)
            #pragma unroll
            for (int fj = 0; fj < 4; ++fj)
                acc[fi][fj] = __builtin_amdgcn_mfma_f32_16x16x32_bf16(
                    ah[fi], blo[fj], acc[fi][fj], 0, 0, 0);
        bf16x8 alo[4];
        #pragma unroll
        for (int f = 0; f < 4; ++f) alo[f] = *(const bf16x8*)(lb + 8192 + byteA[f]);
        #pragma unroll
        for (int fi = 0; fi < 4; ++fi)
            #pragma unroll
            for (int fj = 0; fj < 4; ++fj)
                acc[fi][fj] = __builtin_amdgcn_mfma_f32_16x16x32_bf16(
                    alo[fi], bh[fj], acc[fi][fj], 0, 0, 0);

        PIPE_SYNC();  // drain next-step staging loads; all waves done reading lb
        cur ^= 1;

        if ((ks & 7) == 7) {
            // epilogue for ct = ks>>3 (runs after sync -> overlaps next stage issue)
            // score = e2[c] - 2*dot; C/D layout col=lane&15, row=(lane>>4)*4+reg
            const int cb = cslice0 + (ks >> 3) * BN + wc0;
            #pragma unroll
            for (int fj = 0; fj < 4; ++fj) {
                const int c = cb + fj * 16 + lane15;
                const float e2v = e2g[c];
                #pragma unroll
                for (int fi = 0; fi < 4; ++fi)
                    #pragma unroll
                    for (int r = 0; r < 4; ++r) {
                        float sc = e2v - 2.0f * acc[fi][fj][r];
                        const int slot = fi * 4 + r;
                        if (sc < best[slot]) { best[slot] = sc; bidx[slot] = c; }
                    }
            }
            #pragma unroll
            for (int fi = 0; fi < 4; ++fi)
                #pragma unroll
                for (int fj = 0; fj < 4; ++fj) acc[fi][fj] = (f32x4){0.f, 0.f, 0.f, 0.f};
        }
    }

    // reduce across the 16 lanes sharing each row; ties -> lowest index
    #pragma unroll
    for (int slot = 0; slot < 16; ++slot) {
        float v = best[slot];
        int ix = bidx[slot];
        #pragma unroll
        for (int off = 1; off < 16; off <<= 1) {
            float v2 = __shfl_xor(v, off);
            int ix2 = __shfl_xor(ix, off);
            if (v2 < v || (v2 == v && ix2 < ix)) { v = v2; ix = ix2; }
        }
        if (lane15 == 0) {
            int fi = slot >> 2, r = slot & 3;
            int row = row0 + wr0 + fi * 16 + l16 * 4 + r;
            uint32_t u = __float_as_uint(v);
            uint32_t ord = (u & 0x80000000u) ? ~u : (u | 0x80000000u);
            partials[(size_t)(slice * 2 + (wv >> 1)) * N_VEC + row] =
                ((unsigned long long)ord << 32) | (unsigned)ix;
        }
    }
}

// ---------------- fused: per-row min over partials + gather + loss + counts
__global__ __launch_bounds__(256) void finish_kernel(
    const float* __restrict__ x, const float* __restrict__ emb,
    const unsigned long long* __restrict__ partials,
    float* __restrict__ out_ind, float* __restrict__ out_q,
    unsigned* __restrict__ counts, float* __restrict__ loss_acc) {
    __shared__ float partial[4];
    const int wave = threadIdx.x >> 6;
    const int lane = threadIdx.x & 63;
    const int row = blockIdx.x * 4 + wave;

    unsigned long long m = ~0ull;
    if (lane < NPART) m = partials[(size_t)lane * N_VEC + row];
    #pragma unroll
    for (int off = 1; off < NPART; off <<= 1) {
        unsigned long long v = __shfl_xor(m, off);
        if (v < m) m = v;
    }
    m = __shfl(m, 0);
    const int ix = (int)(unsigned)(m & 0xFFFFFFFFull);

    float4 q = *(const float4*)(emb + (size_t)ix * DIM + lane * 4);
    float4 xv = *(const float4*)(x + (size_t)row * DIM + lane * 4);
    *(float4*)(out_q + (size_t)row * DIM + lane * 4) = q;
    float dx = q.x - xv.x, dy = q.y - xv.y, dz = q.z - xv.z, dw = q.w - xv.w;
    float s = dx * dx + dy * dy + dz * dz + dw * dw;
    #pragma unroll
    for (int off = 32; off; off >>= 1) s += __shfl_xor(s, off);
    if (lane == 0) {
        out_ind[row] = (float)ix;
        atomicAdd(&counts[ix], 1u);
        partial[wave] = s;
    }
    __syncthreads();
    if (threadIdx.x == 0)
        atomicAdd(loss_acc, partial[0] + partial[1] + partial[2] + partial[3]);
}

// -------------------------------------------------- entropy / loss finalize
__global__ __launch_bounds__(256) void finalize_kernel(
    const unsigned* __restrict__ counts, const float* __restrict__ loss_acc,
    float* __restrict__ out_scalars) {
    __shared__ float red[256];
    float h = 0.0f;
    for (int c = threadIdx.x; c < M_CODES; c += 256) {
        float p = (float)counts[c] * (1.0f / (float)N_VEC);
        h += p * logf(p + 1e-10f);
    }
    red[threadIdx.x] = h;
    __syncthreads();
    for (int s = 128; s; s >>= 1) {
        if (threadIdx.x < s) red[threadIdx.x] += red[threadIdx.x + s];
        __syncthreads();
    }
    if (threadIdx.x == 0) {
        out_scalars[0] = BETA * loss_acc[0] / (float)(N_VEC * DIM);
        out_scalars[1] = expf(-red[0]);
    }
}

extern "C" void kernel_launch(void* const* d_in, const int* in_sizes, int n_in,
                              void* d_out, int out_size, void* d_ws, size_t ws_size,
                              hipStream_t stream) {
    const float* x = (const float*)d_in[0];
    const float* emb = (const float*)d_in[1];

    float* out = (float*)d_out;
    float* out_q = out;                                   // N*DIM
    float* out_ind = out + (size_t)N_VEC * DIM;           // N
    float* out_scalars = out_ind + N_VEC;                 // 2

    // x hi/lo scratch lives in d_out's quantized region (16 MB, rewritten by finish)
    ushort* xh = (ushort*)out;                            // 8 MB
    ushort* xl = xh + (size_t)N_VEC * DIM;                // 8 MB

    char* wp = (char*)d_ws;
    ushort* eh = (ushort*)wp;  wp += (size_t)M_CODES * DIM * 2;   // 4 MB
    ushort* el = (ushort*)wp;  wp += (size_t)M_CODES * DIM * 2;   // 4 MB
    float* e2 = (float*)wp;    wp += (size_t)M_CODES * 4;         // 32 KB
    unsigned long long* partials = (unsigned long long*)wp;
    wp += (size_t)NPART * N_VEC * 8;                              // 2 MB
    unsigned* counts = (unsigned*)wp; wp += (size_t)M_CODES * 4;  // 32 KB
    float* loss_acc = (float*)wp;                                 // 4 B

    hipMemsetAsync(counts, 0, M_CODES * 4, stream);
    hipMemsetAsync(loss_acc, 0, 4, stream);

    prep_kernel<<<(N_VEC + M_CODES) / 4, 256, 0, stream>>>(x, emb, xh, xl, eh, el, e2);

    hipFuncSetAttribute((const void*)vq_mfma_kernel,
                        hipFuncAttributeMaxDynamicSharedMemorySize, 2 * LDS_HALF);
    vq_mfma_kernel<<<128 * NSLICE, 256, 2 * LDS_HALF, stream>>>(xh, xl, eh, el, e2,
                                                                partials);

    finish_kernel<<<N_VEC / 4, 256, 0, stream>>>(x, emb, partials, out_ind, out_q,
                                                 counts, loss_acc);
    finalize_kernel<<<1, 256, 0, stream>>>(counts, loss_acc, out_scalars);
}

// Round 4
// 271.557 us; speedup vs baseline: 19.7671x; 1.0207x over previous
//
#include <hip/hip_runtime.h>
#include <stdint.h>

// VectorQuantize on MI355X (gfx950) — bf16x3 MFMA distance-GEMM + argmin.
// Round 4: 3-deep LDS ring with counted vmcnt(6) (T3+T4), 256x128 tile,
// 512 threads, e2 in LDS, slice-per-XCD swizzle, fused memsets.
// d_out: [0..N*DIM) quantized (fp32), [N*DIM..+N) ind (fp32), loss, perplexity.

#define N_VEC 16384
#define M_CODES 8192
#define DIM 256
#define BETA 0.25f

#define NSLICE 8
#define SLICE_CODES 1024
#define BM 256
#define BN 128
#define BK 32
#define NPART 16
#define STEP_BYTES 49152          // Xh 16K | Xl 16K | Eh 8K | El 8K
#define RING_BYTES (3 * STEP_BYTES)
#define LDS_TOTAL (RING_BYTES + 4096)   // + e2 slice (1024 f32)
#define NSTEPS 64                 // 8 ct x 8 kc

typedef __attribute__((ext_vector_type(4))) float f32x4;
typedef __attribute__((ext_vector_type(8))) __bf16 bf16x8;

__device__ __forceinline__ void gll16(const void* g, const void* lds_p) {
    __builtin_amdgcn_global_load_lds(
        (const __attribute__((address_space(1))) uint32_t*)(uintptr_t)g,
        (__attribute__((address_space(3))) uint32_t*)(uint32_t)(uintptr_t)lds_p,
        16, 0, 0);
}

__device__ __forceinline__ ushort f2bf(float f) {
    uint32_t u = __float_as_uint(f);
    return (ushort)((u + 0x7FFFu + ((u >> 16) & 1u)) >> 16);  // RNE
}
__device__ __forceinline__ float bf2f(ushort h) {
    return __uint_as_float(((uint32_t)h) << 16);
}

// ---- fused: split fp32 -> bf16 hi/lo for x and e, e2, zero counts/loss ----
__global__ __launch_bounds__(256) void prep_kernel(
    const float* __restrict__ x, const float* __restrict__ emb,
    ushort* __restrict__ xh, ushort* __restrict__ xl,
    ushort* __restrict__ eh, ushort* __restrict__ el,
    float* __restrict__ e2, unsigned* __restrict__ counts,
    float* __restrict__ loss_acc) {
    if (blockIdx.x < 8) {
        int4 z = {0, 0, 0, 0};
        ((int4*)counts)[blockIdx.x * 256 + threadIdx.x] = z;
        if (blockIdx.x == 0 && threadIdx.x == 0) *loss_acc = 0.0f;
    }
    const int wave = threadIdx.x >> 6;
    const int lane = threadIdx.x & 63;
    const int row = blockIdx.x * 4 + wave;

    const float* src;
    ushort* ph;
    ushort* pl;
    bool is_e;
    int er = row - N_VEC;
    if (row < N_VEC) {
        src = x + (size_t)row * DIM;
        ph = xh + (size_t)row * DIM;
        pl = xl + (size_t)row * DIM;
        is_e = false;
    } else {
        src = emb + (size_t)er * DIM;
        ph = eh + (size_t)er * DIM;
        pl = el + (size_t)er * DIM;
        is_e = true;
    }
    float4 v = *(const float4*)(src + lane * 4);
    ushort h0 = f2bf(v.x), h1 = f2bf(v.y), h2 = f2bf(v.z), h3 = f2bf(v.w);
    ushort l0 = f2bf(v.x - bf2f(h0)), l1 = f2bf(v.y - bf2f(h1));
    ushort l2 = f2bf(v.z - bf2f(h2)), l3 = f2bf(v.w - bf2f(h3));
    *(ushort4*)(ph + lane * 4) = make_ushort4(h0, h1, h2, h3);
    *(ushort4*)(pl + lane * 4) = make_ushort4(l0, l1, l2, l3);
    if (is_e) {
        float s = v.x * v.x + v.y * v.y + v.z * v.z + v.w * v.w;
        #pragma unroll
        for (int off = 32; off; off >>= 1) s += __shfl_xor(s, off);
        if (lane == 0) e2[er] = s;
    }
}

// -------------- main: bf16x3 MFMA distance GEMM, 3-deep ring, argmin --------
__global__ __launch_bounds__(512, 2) void vq_mfma_kernel(
    const ushort* __restrict__ xh, const ushort* __restrict__ xl,
    const ushort* __restrict__ eh, const ushort* __restrict__ el,
    const float* __restrict__ e2g, unsigned long long* __restrict__ partials) {
    extern __shared__ char lds[];

    const int t = threadIdx.x;
    const int lane = t & 63;
    const int wv = t >> 6;         // 0..7
    const int lane15 = lane & 15;
    const int l16 = lane >> 4;     // 0..3

    // slice-per-XCD swizzle: blocks sharing an E-slice land on one XCD
    const int slice = blockIdx.x & 7;
    const int rt = blockIdx.x >> 3;       // 0..63
    const int row0 = rt * BM;
    const int cslice0 = slice * SLICE_CODES;

    const int wr0 = (wv & 3) * 64;   // wave row quadrant (0..192)
    const int wc0 = (wv >> 2) * 64;  // wave col half (0 or 64)

    // ---- fragment LDS byte offsets (within a ring slot)
    int byteA[4], byteB[4];
    #pragma unroll
    for (int f = 0; f < 4; ++f) {
        int ra = wr0 + f * 16 + lane15;
        byteA[f] = ra * 64 + (((l16 ^ (ra >> 1)) & 3) << 4);
        int rb = wc0 + f * 16 + lane15;
        byteB[f] = rb * 64 + (((l16 ^ (rb >> 1)) & 3) << 4);
    }

    // ---- staging source addresses (inverse-swizzled global, linear LDS dest)
    const int r_a = t >> 2;                       // 0..127
    const int c_a = ((t & 3) ^ ((t >> 3) & 3));   // 16B chunk 0..3
    const ushort* pxh_a = xh + (size_t)(row0 + r_a) * DIM + c_a * 8;
    const ushort* pxh_b = pxh_a + (size_t)128 * DIM;
    const ushort* pxl_a = xl + (size_t)(row0 + r_a) * DIM + c_a * 8;
    const ushort* pxl_b = pxl_a + (size_t)128 * DIM;
    const ushort* peh = eh + (size_t)(cslice0 + r_a) * DIM + c_a * 8;
    const ushort* pel = el + (size_t)(cslice0 + r_a) * DIM + c_a * 8;

    // ---- preload e2 slice into LDS (keeps epilogue off the vmcnt counter)
    float* e2s = (float*)(lds + RING_BYTES);
    e2s[t] = e2g[cslice0 + t];
    e2s[t + 512] = e2g[cslice0 + t + 512];
    asm volatile("s_waitcnt lgkmcnt(0)" ::: "memory");

    float best[16];
    int bidx[16];
    #pragma unroll
    for (int s = 0; s < 16; ++s) { best[s] = __uint_as_float(0x7f800000u); bidx[s] = 0; }

    f32x4 acc[4][4];
    #pragma unroll
    for (int fi = 0; fi < 4; ++fi)
        #pragma unroll
        for (int fj = 0; fj < 4; ++fj) acc[fi][fj] = (f32x4){0.f, 0.f, 0.f, 0.f};

    auto stage = [&](int sidx) {
        const int ct = sidx >> 3;
        const int kc = sidx & 7;
        char* base = lds + (sidx % 3) * STEP_BYTES + wv * 1024;
        const int xo = kc * 32;
        const size_t eo = ((size_t)ct << 15) + xo;  // ct*BN*DIM + kc*32
        gll16(pxh_a + xo, base);
        gll16(pxh_b + xo, base + 8192);
        gll16(pxl_a + xo, base + 16384);
        gll16(pxl_b + xo, base + 24576);
        gll16(peh + eo, base + 32768);
        gll16(pel + eo, base + 40960);
    };

    auto compute = [&](int sidx) {
        const char* lb = lds + (sidx % 3) * STEP_BYTES;
        bf16x8 ah[4], alo[4], bh[4], blo[4];
        #pragma unroll
        for (int f = 0; f < 4; ++f) {
            ah[f] = *(const bf16x8*)(lb + byteA[f]);
            alo[f] = *(const bf16x8*)(lb + 16384 + byteA[f]);
            bh[f] = *(const bf16x8*)(lb + 32768 + byteB[f]);
            blo[f] = *(const bf16x8*)(lb + 40960 + byteB[f]);
        }
        __builtin_amdgcn_s_setprio(1);
        #pragma unroll
        for (int fi = 0; fi < 4; ++fi)
            #pragma unroll
            for (int fj = 0; fj < 4; ++fj)
                acc[fi][fj] = __builtin_amdgcn_mfma_f32_16x16x32_bf16(
                    ah[fi], bh[fj], acc[fi][fj], 0, 0, 0);
        #pragma unroll
        for (int fi = 0; fi < 4; ++fi)
            #pragma unroll
            for (int fj = 0; fj < 4; ++fj)
                acc[fi][fj] = __builtin_amdgcn_mfma_f32_16x16x32_bf16(
                    ah[fi], blo[fj], acc[fi][fj], 0, 0, 0);
        #pragma unroll
        for (int fi = 0; fi < 4; ++fi)
            #pragma unroll
            for (int fj = 0; fj < 4; ++fj)
                acc[fi][fj] = __builtin_amdgcn_mfma_f32_16x16x32_bf16(
                    alo[fi], bh[fj], acc[fi][fj], 0, 0, 0);
        __builtin_amdgcn_s_setprio(0);

        if ((sidx & 7) == 7) {
            const int ct = sidx >> 3;
            const int cb = cslice0 + ct * BN + wc0;
            #pragma unroll
            for (int fj = 0; fj < 4; ++fj) {
                const int cl = ct * BN + wc0 + fj * 16 + lane15;
                const float e2v = e2s[cl];
                const int c = cb + fj * 16 + lane15;
                #pragma unroll
                for (int fi = 0; fi < 4; ++fi)
                    #pragma unroll
                    for (int r = 0; r < 4; ++r) {
                        float sc = e2v - 2.0f * acc[fi][fj][r];
                        const int slot = fi * 4 + r;
                        if (sc < best[slot]) { best[slot] = sc; bidx[slot] = c; }
                    }
            }
            #pragma unroll
            for (int fi = 0; fi < 4; ++fi)
                #pragma unroll
                for (int fj = 0; fj < 4; ++fj) acc[fi][fj] = (f32x4){0.f, 0.f, 0.f, 0.f};
        }
    };

    // prologue: 2 steps in flight
    stage(0);
    stage(1);

    // steady state: at step s entry, outstanding = s's 6 (oldest) + (s+1)'s 6.
    // vmcnt(6) drains step-s loads; barrier publishes them + frees slot (s+2)%3.
    for (int sidx = 0; sidx < NSTEPS - 1; ++sidx) {
        asm volatile("s_waitcnt vmcnt(6)" ::: "memory");
        __builtin_amdgcn_s_barrier();
        if (sidx < NSTEPS - 2) stage(sidx + 2);
        compute(sidx);
    }
    asm volatile("s_waitcnt vmcnt(0)" ::: "memory");
    __builtin_amdgcn_s_barrier();
    compute(NSTEPS - 1);

    // reduce across the 16 lanes sharing each row; ties -> lowest index
    #pragma unroll
    for (int slot = 0; slot < 16; ++slot) {
        float v = best[slot];
        int ix = bidx[slot];
        #pragma unroll
        for (int off = 1; off < 16; off <<= 1) {
            float v2 = __shfl_xor(v, off);
            int ix2 = __shfl_xor(ix, off);
            if (v2 < v || (v2 == v && ix2 < ix)) { v = v2; ix = ix2; }
        }
        if (lane15 == 0) {
            int fi = slot >> 2, r = slot & 3;
            int row = row0 + wr0 + fi * 16 + l16 * 4 + r;
            uint32_t u = __float_as_uint(v);
            uint32_t ord = (u & 0x80000000u) ? ~u : (u | 0x80000000u);
            partials[(size_t)(slice * 2 + (wv >> 2)) * N_VEC + row] =
                ((unsigned long long)ord << 32) | (unsigned)ix;
        }
    }
}

// ---------------- fused: per-row min over partials + gather + loss + counts
__global__ __launch_bounds__(256) void finish_kernel(
    const float* __restrict__ x, const float* __restrict__ emb,
    const unsigned long long* __restrict__ partials,
    float* __restrict__ out_ind, float* __restrict__ out_q,
    unsigned* __restrict__ counts, float* __restrict__ loss_acc) {
    __shared__ float partial[4];
    const int wave = threadIdx.x >> 6;
    const int lane = threadIdx.x & 63;
    const int row = blockIdx.x * 4 + wave;

    unsigned long long m = ~0ull;
    if (lane < NPART) m = partials[(size_t)lane * N_VEC + row];
    #pragma unroll
    for (int off = 1; off < NPART; off <<= 1) {
        unsigned long long v = __shfl_xor(m, off);
        if (v < m) m = v;
    }
    m = __shfl(m, 0);
    const int ix = (int)(unsigned)(m & 0xFFFFFFFFull);

    float4 q = *(const float4*)(emb + (size_t)ix * DIM + lane * 4);
    float4 xv = *(const float4*)(x + (size_t)row * DIM + lane * 4);
    *(float4*)(out_q + (size_t)row * DIM + lane * 4) = q;
    float dx = q.x - xv.x, dy = q.y - xv.y, dz = q.z - xv.z, dw = q.w - xv.w;
    float s = dx * dx + dy * dy + dz * dz + dw * dw;
    #pragma unroll
    for (int off = 32; off; off >>= 1) s += __shfl_xor(s, off);
    if (lane == 0) {
        out_ind[row] = (float)ix;
        atomicAdd(&counts[ix], 1u);
        partial[wave] = s;
    }
    __syncthreads();
    if (threadIdx.x == 0)
        atomicAdd(loss_acc, partial[0] + partial[1] + partial[2] + partial[3]);
}

// -------------------------------------------------- entropy / loss finalize
__global__ __launch_bounds__(256) void finalize_kernel(
    const unsigned* __restrict__ counts, const float* __restrict__ loss_acc,
    float* __restrict__ out_scalars) {
    __shared__ float red[256];
    float h = 0.0f;
    for (int c = threadIdx.x; c < M_CODES; c += 256) {
        float p = (float)counts[c] * (1.0f / (float)N_VEC);
        h += p * logf(p + 1e-10f);
    }
    red[threadIdx.x] = h;
    __syncthreads();
    for (int s = 128; s; s >>= 1) {
        if (threadIdx.x < s) red[threadIdx.x] += red[threadIdx.x + s];
        __syncthreads();
    }
    if (threadIdx.x == 0) {
        out_scalars[0] = BETA * loss_acc[0] / (float)(N_VEC * DIM);
        out_scalars[1] = expf(-red[0]);
    }
}

extern "C" void kernel_launch(void* const* d_in, const int* in_sizes, int n_in,
                              void* d_out, int out_size, void* d_ws, size_t ws_size,
                              hipStream_t stream) {
    const float* x = (const float*)d_in[0];
    const float* emb = (const float*)d_in[1];

    float* out = (float*)d_out;
    float* out_q = out;                                   // N*DIM
    float* out_ind = out + (size_t)N_VEC * DIM;           // N
    float* out_scalars = out_ind + N_VEC;                 // 2

    // x hi/lo scratch lives in d_out's quantized region (rewritten by finish)
    ushort* xh = (ushort*)out;                            // 8 MB
    ushort* xl = xh + (size_t)N_VEC * DIM;                // 8 MB

    char* wp = (char*)d_ws;
    ushort* eh = (ushort*)wp;  wp += (size_t)M_CODES * DIM * 2;   // 4 MB
    ushort* el = (ushort*)wp;  wp += (size_t)M_CODES * DIM * 2;   // 4 MB
    float* e2 = (float*)wp;    wp += (size_t)M_CODES * 4;         // 32 KB
    unsigned long long* partials = (unsigned long long*)wp;
    wp += (size_t)NPART * N_VEC * 8;                              // 2 MB
    unsigned* counts = (unsigned*)wp; wp += (size_t)M_CODES * 4;  // 32 KB
    float* loss_acc = (float*)wp;                                 // 4 B

    prep_kernel<<<(N_VEC + M_CODES) / 4, 256, 0, stream>>>(x, emb, xh, xl, eh, el,
                                                           e2, counts, loss_acc);

    hipFuncSetAttribute((const void*)vq_mfma_kernel,
                        hipFuncAttributeMaxDynamicSharedMemorySize, LDS_TOTAL);
    vq_mfma_kernel<<<(N_VEC / BM) * NSLICE, 512, LDS_TOTAL, stream>>>(
        xh, xl, eh, el, e2, partials);

    finish_kernel<<<N_VEC / 4, 256, 0, stream>>>(x, emb, partials, out_ind, out_q,
                                                 counts, loss_acc);
    finalize_kernel<<<1, 256, 0, stream>>>(counts, loss_acc, out_scalars);
}